// Round 4
// baseline (175.174 us; speedup 1.0000x reference)
//
#include <hip/hip_runtime.h>
#include <cstdint>
#include <cstddef>

// Problem constants (fixed by the reference)
#define B_      32
#define N_      8400
#define C_      80
#define NC      672000        // N_*C_
#define NCV4    168000        // NC/4
#define NBINS   4096
#define TOPK    1024
#define MAXDET  300
#define CANDCAP 4096
#define NSLICE  16
#define SLICE_V4 10500        // NCV4 / NSLICE
#define NBKT    8             // score bins 4088..4095 (all x in [0.998..1))
#define SEGB    64            // per-(batch,bucket,slice) cap (mean 10.25, 17 sigma)
#define BSORT   256           // per-bucket cap (mean 164, 7.2 sigma)

// Static stage threshold: score >= 4088/4096 = 0.998046875.
// Expected candidates/batch = 672000*8/4096 = 1312 (sd ~36). Bucket = bin-4088
// partitions candidates into 8 ORDER-DISJOINT groups (floor is monotone, float
// bits are monotone): buckets concatenated 7..0 == exact lax.top_k order
// (score desc, index asc via key low bits). Violating inputs take the exact
// in-kernel histogram fallback (never on bench input).
#define STAGE_THRESH 0.998046875f

// Workspace layout (bytes). Cross-kernel interface is COMPRESSED: class+valid
// packed to 1 byte/position (clsv), keep as 1 byte/position.
#define WS_SEGKEYS  0           // 32*8*16*64*8 = 2097152
#define WS_SEGCNT   2097152     // 32*8*16*4    = 16384
#define WS_TOPSCORE 2113536     // 32*1024*4    = 131072
#define WS_TOPBOX   2244608     // 32*1024*16   = 524288
#define WS_CLSV     2768896     // 32*1024*1    = 32768   (0x80|class, 0 = invalid)
#define WS_KEEP     2801664     // 32*1024*1    = 32768

// Output layout (float32, concatenated): boxes[32][300][4], scores[32][300],
// labels[32][300], n_valid[32]
#define OUT_SCORES  38400
#define OUT_LABELS  48000
#define OUT_NVALID  57600

// ---------------------------------------------------------------------------
// K1: single-pass filter+stage into PRIVATE per-(batch,bucket,slice) segments.
// key = (bits(v)<<32) | ~flat_idx. 8 LDS counters per block; plain global
// stores; no global atomics, no pre-zeroing (raw counts let K2 detect
// overflow -> fallback). Memory-bound: 86 MB read ~= 14 us (at roofline).
__global__ __launch_bounds__(256) void stage_kernel(const float4* __restrict__ scores4,
                                                    unsigned* __restrict__ segCnt,
                                                    unsigned long long* __restrict__ segKeys) {
    __shared__ unsigned lcnt[NBKT];
    int b = blockIdx.x, sl = blockIdx.y, tid = threadIdx.x;
    if (tid < NBKT) lcnt[tid] = 0;
    __syncthreads();
    const float4* s = scores4 + (size_t)b * NCV4 + (size_t)sl * SLICE_V4;
    for (int i = tid; i < SLICE_V4; i += 256) {
        float4 v = s[i];
        float c[4] = {v.x, v.y, v.z, v.w};
        unsigned flat0 = ((unsigned)sl * SLICE_V4 + (unsigned)i) * 4u;
        #pragma unroll
        for (int kc = 0; kc < 4; ++kc) {
            float x = (c[kc] > 0.001f) ? c[kc] : 0.0f;
            if (x >= STAGE_THRESH) {
                int bin = (int)(x * 4096.0f);             // exact: x * 2^12
                bin = bin > (NBINS - 1) ? (NBINS - 1) : bin;
                int bkt = bin - 4088;                      // 0..7
                unsigned p = atomicAdd(&lcnt[bkt], 1u);
                if (p < (unsigned)SEGB)
                    segKeys[(((size_t)(b * NBKT + bkt)) * NSLICE + sl) * SEGB + p] =
                        ((unsigned long long)__float_as_uint(x) << 32) |
                        (unsigned long long)(0xFFFFFFFFu - (flat0 + kc));
            }
        }
    }
    __syncthreads();
    if (tid < NBKT) segCnt[(b * NBKT + tid) * NSLICE + sl] = lcnt[tid];
}

// ---------------------------------------------------------------------------
// K2: one WAVE per (batch,bucket) — 256 parallel blocks. Fast path: gather the
// bucket's 16 slice-segments with all loads in flight, then RANK-AND-SCATTER:
// pos = bucket_base + #{greater keys in bucket}. Keys unique => exact
// permutation == lax.top_k order. Writes topScore/topBox + packed clsv byte;
// bkt-0 block also zeroes keep (1 KB, one uint4 store round). Invalid inputs:
// block (b,0) runs the exact histogram fallback (never on bench input).
__global__ __launch_bounds__(64) void select_kernel(
        const float4* __restrict__ scores4,
        const unsigned long long* __restrict__ segKeys,
        const unsigned* __restrict__ segCnt,
        const float4* __restrict__ boxes4,
        float* __restrict__ topScore,
        float4* __restrict__ topBox4,
        unsigned char* __restrict__ clsv,
        unsigned char* __restrict__ keepB) {
    __shared__ unsigned long long kbuf[CANDCAP];    // 32 KB (fast path uses 260)
    __shared__ unsigned scnt2[NBKT * NSLICE];       // all 128 segment counts
    __shared__ unsigned spref[NSLICE];              // own-bucket slice prefix
    __shared__ unsigned scnt;
    __shared__ int s_cut;
    int b = blockIdx.x, bkt = blockIdx.y, lane = threadIdx.x;

    // P0: load all 128 counts in ONE 8B load/lane; every lane redundantly
    // computes bucket sums / validity / base from LDS broadcasts (lockstep).
    {
        uint2 cc = ((const uint2*)(segCnt + b * NBKT * NSLICE))[lane];
        scnt2[lane * 2]     = cc.x;
        scnt2[lane * 2 + 1] = cc.y;
    }
    __threadfence_block();
    unsigned M = 0, base = 0, n = 0; int valid = 1;
    #pragma unroll
    for (int t = 0; t < NBKT; ++t) {
        unsigned s2 = 0, mx = 0;
        #pragma unroll
        for (int sl = 0; sl < NSLICE; ++sl) {
            unsigned v = scnt2[t * NSLICE + sl];
            s2 += v; mx = v > mx ? v : mx;
        }
        if (mx > (unsigned)SEGB || s2 > (unsigned)BSORT) valid = 0;
        M += s2;
        if (t > bkt) base += s2;
        if (t == bkt) n = s2;
    }
    if (M < (unsigned)TOPK || M > (unsigned)CANDCAP) valid = 0;

    if (valid) {
        if (bkt == 0) {                              // zero keep BEFORE any return
            uint4 z; z.x = 0u; z.y = 0u; z.z = 0u; z.w = 0u;
            ((uint4*)(keepB + (size_t)b * TOPK))[lane] = z;
        }
        if (base >= (unsigned)TOPK || n == 0) return;
        // slice prefixes within own bucket
        if (lane < NSLICE) {
            unsigned acc = 0;
            for (int s2 = 0; s2 < lane; ++s2) acc += scnt2[bkt * NSLICE + s2];
            spref[lane] = acc;
        }
        __threadfence_block();
        // P1: gather — 16 segments concurrently, 4 lanes each (max load ILP)
        {
            int sl = lane & 15;
            int eo = lane >> 4;                      // 0..3
            unsigned cA = scnt2[bkt * NSLICE + sl];  // <= SEGB in valid path
            unsigned b0 = spref[sl];
            const unsigned long long* src =
                segKeys + (((size_t)(b * NBKT + bkt)) * NSLICE + sl) * SEGB;
            for (int e = eo; e < (int)cA; e += 4) kbuf[b0 + e] = src[e];
            if (lane < 4) kbuf[n + lane] = 0ull;     // pad for 4-wide rank loop
        }
        __threadfence_block();
        // P2: rank-and-scatter, 4 keys/lane, 4 independent reads per iter.
        int j0 = lane, j1 = lane + 64, j2 = lane + 128, j3 = lane + 192;
        unsigned long long k0 = (j0 < (int)n) ? kbuf[j0] : 0ull;
        unsigned long long k1 = (j1 < (int)n) ? kbuf[j1] : 0ull;
        unsigned long long k2 = (j2 < (int)n) ? kbuf[j2] : 0ull;
        unsigned long long k3 = (j3 < (int)n) ? kbuf[j3] : 0ull;
        unsigned r0 = 0, r1 = 0, r2 = 0, r3 = 0;
        for (unsigned i = 0; i < n; i += 4) {        // pad keys are 0: never >
            unsigned long long a = kbuf[i], b2 = kbuf[i + 1];
            unsigned long long c2 = kbuf[i + 2], d2 = kbuf[i + 3];
            r0 += (unsigned)(a > k0) + (unsigned)(b2 > k0) +
                  (unsigned)(c2 > k0) + (unsigned)(d2 > k0);
            r1 += (unsigned)(a > k1) + (unsigned)(b2 > k1) +
                  (unsigned)(c2 > k1) + (unsigned)(d2 > k1);
            r2 += (unsigned)(a > k2) + (unsigned)(b2 > k2) +
                  (unsigned)(c2 > k2) + (unsigned)(d2 > k2);
            r3 += (unsigned)(a > k3) + (unsigned)(b2 > k3) +
                  (unsigned)(c2 > k3) + (unsigned)(d2 > k3);
        }
        #pragma unroll
        for (int q = 0; q < 4; ++q) {
            int j = q == 0 ? j0 : q == 1 ? j1 : q == 2 ? j2 : j3;
            unsigned long long k = q == 0 ? k0 : q == 1 ? k1 : q == 2 ? k2 : k3;
            unsigned r = q == 0 ? r0 : q == 1 ? r1 : q == 2 ? r2 : r3;
            if (j < (int)n) {
                unsigned pos = base + r;
                if (pos < (unsigned)TOPK) {
                    float sc = __uint_as_float((unsigned)(k >> 32));
                    unsigned idx = 0xFFFFFFFFu - (unsigned)(k & 0xFFFFFFFFull);
                    if (idx >= (unsigned)NC) idx = 0;    // defensive
                    unsigned bi = idx / (unsigned)C_;
                    unsigned cl = idx - bi * (unsigned)C_;
                    topScore[b * TOPK + pos] = sc;
                    topBox4[b * TOPK + pos] = boxes4[(size_t)b * N_ + bi];
                    clsv[(size_t)b * TOPK + pos] = (unsigned char)(0x80u | cl);
                }
            }
        }
        return;
    }

    // ---- exact fallback: only block (b, bkt=0); single wave, fences only.
    if (bkt != 0) return;
    {
        uint4 z; z.x = 0u; z.y = 0u; z.z = 0u; z.w = 0u;
        ((uint4*)(keepB + (size_t)b * TOPK))[lane] = z;
    }
    unsigned* fh = (unsigned*)kbuf;      // aliases kbuf; dead before kbuf written
    for (int i2 = lane; i2 < NBINS; i2 += 64) fh[i2] = 0;
    if (lane == 0) scnt = 0;
    __threadfence_block();
    const float4* s = scores4 + (size_t)b * NCV4;
    for (int i2 = lane; i2 < NCV4; i2 += 64) {
        float4 v = s[i2];
        float c4[4] = {v.x, v.y, v.z, v.w};
        #pragma unroll
        for (int kc = 0; kc < 4; ++kc) {
            float x = (c4[kc] > 0.001f) ? c4[kc] : 0.0f;
            int bin = (int)(x * 4096.0f);
            bin = bin > (NBINS - 1) ? (NBINS - 1) : bin;
            atomicAdd(&fh[bin], 1u);
        }
    }
    __threadfence_block();
    if (lane == 0) {
        unsigned acc = 0; int cb = 0;
        for (int bin = NBINS - 1; bin >= 0; --bin) {
            acc += fh[bin];
            if (acc >= (unsigned)TOPK) { cb = bin; break; }
        }
        s_cut = cb;
    }
    __threadfence_block();               // lane0's fh reads done (lockstep)
    int cb = s_cut;
    for (int i2 = lane; i2 < NCV4; i2 += 64) {
        float4 v = s[i2];
        float c4[4] = {v.x, v.y, v.z, v.w};
        unsigned flat0 = (unsigned)i2 * 4u;
        #pragma unroll
        for (int kc = 0; kc < 4; ++kc) {
            float x = (c4[kc] > 0.001f) ? c4[kc] : 0.0f;
            int bin = (int)(x * 4096.0f);
            bin = bin > (NBINS - 1) ? (NBINS - 1) : bin;
            if (bin >= cb) {
                unsigned p = atomicAdd(&scnt, 1u);
                if (p < (unsigned)CANDCAP)
                    kbuf[p] = ((unsigned long long)__float_as_uint(x) << 32) |
                              (unsigned long long)(0xFFFFFFFFu - (flat0 + kc));
            }
        }
    }
    __threadfence_block();
    unsigned M2 = scnt; if (M2 > (unsigned)CANDCAP) M2 = CANDCAP;
    int S = (M2 <= 1024u) ? 1024 : (M2 <= 2048u ? 2048 : CANDCAP);
    for (int i2 = (int)M2 + lane; i2 < S; i2 += 64) kbuf[i2] = 0ull;
    __threadfence_block();
    for (int kk = 2; kk <= S; kk <<= 1) {
        for (int j = kk >> 1; j > 0; j >>= 1) {
            for (int t = lane; t < S; t += 64) {
                int l = t ^ j;
                if (l > t) {
                    unsigned long long a0 = kbuf[t], c0 = kbuf[l];
                    bool sw = ((t & kk) == 0) ? (a0 < c0) : (a0 > c0);
                    if (sw) { kbuf[t] = c0; kbuf[l] = a0; }
                }
            }
            __threadfence_block();
        }
    }
    for (int r = lane; r < TOPK; r += 64) {
        unsigned long long key = kbuf[r];
        float sc = __uint_as_float((unsigned)(key >> 32));
        unsigned idx = 0xFFFFFFFFu - (unsigned)(key & 0xFFFFFFFFull);
        if (idx >= (unsigned)NC) idx = 0;
        unsigned bi = idx / (unsigned)C_;
        unsigned cl = idx - bi * (unsigned)C_;
        topScore[b * TOPK + r] = sc;
        topBox4[b * TOPK + r] = boxes4[(size_t)b * N_ + bi];
        clsv[(size_t)b * TOPK + r] =
            (unsigned char)((sc > 0.001f ? 0x80u : 0u) | cl);
    }
}

// ---------------------------------------------------------------------------
// K3: greedy NMS. grid (B, 20) x 256 threads: 4 waves/block, wave w handles
// class 4*g+w — same 2560-way wave parallelism as before but 4x fewer
// dispatch packets, and the block BULK-LOADS the batch interface (clsv 1 KB +
// topBox4 16 KB) into LDS with coalesced up-front loads, replacing per-
// candidate random L3 gathers. Per-wave logic identical to round 3 (lockstep,
// threadfence_block, __fmul_rn IoU). Cross-class IoU is exactly 0 (offset gap
// 4096 >> max box 640) => per-class greedy == reference's sequential loop.
#define CLS_CAP 256
#define NMS_CPB 4             // classes (=waves) per block
__global__ __launch_bounds__(256) void nms_kernel(const unsigned char* __restrict__ clsv,
                                                  const float4* __restrict__ topBox4,
                                                  unsigned char* __restrict__ keepB) {
    __shared__ float4 sBox[TOPK];                       // 16 KB
    __shared__ unsigned sClsv[TOPK / 4];                // 1 KB (uint view)
    __shared__ unsigned short spos[NMS_CPB][CLS_CAP];
    __shared__ float by1[NMS_CPB][CLS_CAP], bx1[NMS_CPB][CLS_CAP];
    __shared__ float by2[NMS_CPB][CLS_CAP], bx2[NMS_CPB][CLS_CAP];
    __shared__ float barea[NMS_CPB][CLS_CAP];
    __shared__ unsigned char sup[NMS_CPB][CLS_CAP];
    int b = blockIdx.x, g = blockIdx.y, tid = threadIdx.x;
    int lane = tid & 63, wave = tid >> 6;
    unsigned char* kp = keepB + (size_t)b * TOPK;

    // bulk coalesced staging: all loads independent, issued up-front
    sClsv[tid] = ((const unsigned*)(clsv + (size_t)b * TOPK))[tid];
    #pragma unroll
    for (int r = 0; r < 4; ++r)
        sBox[r * 256 + tid] = topBox4[(size_t)b * TOPK + r * 256 + tid];
    __syncthreads();     // waves diverge after this; no more block barriers

    int c = g * NMS_CPB + wave;                          // 0..79
    // extraction from LDS: lane's 16 consecutive bytes = 4 uints
    unsigned d0 = sClsv[lane * 4 + 0], d1 = sClsv[lane * 4 + 1];
    unsigned d2 = sClsv[lane * 4 + 2], d3 = sClsv[lane * 4 + 3];
    unsigned target = 0x80u | (unsigned)c;
    unsigned mmask = 0; int cnt = 0;
    #pragma unroll
    for (int t = 0; t < 16; ++t) {
        unsigned d = (t < 4) ? d0 : (t < 8) ? d1 : (t < 12) ? d2 : d3;
        unsigned v = (d >> ((t & 3) * 8)) & 0xffu;
        if (v == target) { mmask |= (1u << t); ++cnt; }
    }
    // inclusive wave prefix over per-lane counts
    int x = cnt;
    #pragma unroll
    for (int o = 1; o < 64; o <<= 1) {
        int y = __shfl_up(x, o, 64);
        if (lane >= o) x += y;
    }
    int pre = x - cnt;
    int m = __shfl(x, 63, 64);
    // place own candidates: ascending (lane, t) == ascending pos == score desc
    int slot = pre;
    #pragma unroll
    for (int t = 0; t < 16; ++t) {
        if ((mmask >> t) & 1u) {
            if (slot < CLS_CAP) spos[wave][slot] = (unsigned short)(lane * 16 + t);
            ++slot;
        }
    }
    int m2 = m < CLS_CAP ? m : CLS_CAP;
    __threadfence_block();
    // per-slot box setup — boxes come from LDS now (no global latency)
    float off = (float)c * 4096.0f;         // exact
    for (int j = lane; j < m2; j += 64) {
        int p = spos[wave][j];
        float4 tb = sBox[p];
        float y1 = tb.x + off, x1 = tb.y + off;
        float y2 = tb.z + off, x2 = tb.w + off;
        by1[wave][j] = y1; bx1[wave][j] = x1; by2[wave][j] = y2; bx2[wave][j] = x2;
        barea[wave][j] = __fmul_rn((x2 - x1) + 1.0f, (y2 - y1) + 1.0f);
        sup[wave][j] = 0;
    }
    __threadfence_block();
    int cur = 0;
    while (cur < m2) {
        // invariant: slot `cur` is unsuppressed -> kept
        if (lane == 0) kp[spos[wave][cur]] = 1;
        float cy1 = by1[wave][cur], cx1 = bx1[wave][cur];
        float cy2 = by2[wave][cur], cx2 = bx2[wave][cur];
        float carea = barea[wave][cur];
        for (int j = cur + 1 + lane; j < m2; j += 64) {
            if (!sup[wave][j]) {
                float yy1 = fmaxf(cy1, by1[wave][j]), xx1 = fmaxf(cx1, bx1[wave][j]);
                float yy2 = fminf(cy2, by2[wave][j]), xx2 = fminf(cx2, bx2[wave][j]);
                float w2 = fmaxf(0.0f, (xx2 - xx1) + 1.0f);
                float h2 = fmaxf(0.0f, (yy2 - yy1) + 1.0f);
                float inter = __fmul_rn(w2, h2);
                float denom = (carea + barea[wave][j]) - inter;
                float iou = inter / denom;
                if (iou > 0.7f) sup[wave][j] = 1;
            }
        }
        __threadfence_block();
        int nxt = m2;
        for (int j = cur + 1 + lane; j < m2; j += 64)
            if (!sup[wave][j]) { nxt = j; break; }
        for (int o = 32; o > 0; o >>= 1) {
            int other = __shfl_xor(nxt, o, 64);
            nxt = nxt < other ? nxt : other;
        }
        cur = nxt;
    }
}

// ---------------------------------------------------------------------------
// K4: stable top-300 of final_scores: kept positions in order, then suppressed
// positions in order (score-0 ties break by lower index). keep is 0/1 uchar:
// ballot/popcount scan — 2 barriers. Labels derived from packed clsv.
__global__ __launch_bounds__(1024) void finalize_kernel(const float* __restrict__ topScore,
                                                        const float4* __restrict__ topBox4,
                                                        const unsigned char* __restrict__ clsv,
                                                        const unsigned char* __restrict__ keepB,
                                                        float* __restrict__ out) {
    __shared__ int wsum[16];
    __shared__ int sel[MAXDET];
    int b = blockIdx.x;
    int tid = threadIdx.x;
    int lane = tid & 63;
    int wave = tid >> 6;
    int kp = keepB[(size_t)b * TOPK + tid];
    unsigned long long mb = __ballot(kp != 0);
    int wpre = __popcll(mb & ((1ull << lane) - 1ull));
    if (lane == 0) wsum[wave] = __popcll(mb);
    __syncthreads();
    int wbase = 0, nk = 0;
    #pragma unroll
    for (int t = 0; t < 16; ++t) {
        int v = wsum[t];
        if (t < wave) wbase += v;
        nk += v;
    }
    int kexcl = wbase + wpre;    // exclusive kept rank
    int sexcl = tid - kexcl;     // exclusive suppressed rank
    if (kp) {
        if (kexcl < MAXDET) sel[kexcl] = tid;
    } else {
        int slot = nk + sexcl;
        if (slot < MAXDET) sel[slot] = tid;
    }
    __syncthreads();
    if (tid < MAXDET) {
        int p = sel[tid];
        float sc = (tid < nk) ? topScore[b * TOPK + p] : 0.0f;
        float4 tb = topBox4[(size_t)b * TOPK + p];
        float* ob = out + ((size_t)b * MAXDET + tid) * 4;
        ob[0] = tb.x; ob[1] = tb.y; ob[2] = tb.z; ob[3] = tb.w;
        out[OUT_SCORES + b * MAXDET + tid] = sc;
        out[OUT_LABELS + b * MAXDET + tid] =
            (float)(clsv[(size_t)b * TOPK + p] & 0x7f);
    }
    if (tid == 0) out[OUT_NVALID + b] = (float)(nk < MAXDET ? nk : MAXDET);
}

// ---------------------------------------------------------------------------
extern "C" void kernel_launch(void* const* d_in, const int* in_sizes, int n_in,
                              void* d_out, int out_size, void* d_ws, size_t ws_size,
                              hipStream_t stream) {
    const float* boxes  = (const float*)d_in[0];   // (32, 8400, 4)
    const float* scores = (const float*)d_in[1];   // (32, 8400, 80)
    float* out = (float*)d_out;
    char* ws = (char*)d_ws;

    unsigned long long* segKeys = (unsigned long long*)(ws + WS_SEGKEYS);
    unsigned* segCnt = (unsigned*)(ws + WS_SEGCNT);
    float* topScore = (float*)(ws + WS_TOPSCORE);
    float4* topBox4 = (float4*)(ws + WS_TOPBOX);
    unsigned char* clsv = (unsigned char*)(ws + WS_CLSV);
    unsigned char* keepB = (unsigned char*)(ws + WS_KEEP);

    const float4* scores4 = (const float4*)scores;
    const float4* boxes4  = (const float4*)boxes;

    stage_kernel<<<dim3(B_, NSLICE), 256, 0, stream>>>(scores4, segCnt, segKeys);
    select_kernel<<<dim3(B_, NBKT), 64, 0, stream>>>(scores4, segKeys, segCnt, boxes4,
                                                     topScore, topBox4, clsv, keepB);
    nms_kernel<<<dim3(B_, C_ / NMS_CPB), 256, 0, stream>>>(clsv, topBox4, keepB);
    finalize_kernel<<<B_, 1024, 0, stream>>>(topScore, topBox4, clsv, keepB, out);
}